// Round 1
// baseline (1324.167 us; speedup 1.0000x reference)
//
#include <hip/hip_runtime.h>
#include <math.h>

// Problem constants
#define BB   32
#define CC   256
#define HH   32
#define WW   32
#define DD   256
#define KK   4096
#define HW   1024
#define NPIX 32768   // B*H*W
#define NELE 8388608 // B*D*H*W

// ---------------- K0: zero counts + accumulators ----------------
__global__ void k_zero(int* __restrict__ counts, float* __restrict__ accum) {
    int i = blockIdx.x * 256 + threadIdx.x;
    if (i < KK) counts[i] = 0;
    if (i < 2)  accum[i]  = 0.0f;
}

// ---------------- K1: e_norm[k] = ||emb[k]||^2 ----------------
__global__ void k_enorm(const float* __restrict__ emb, float* __restrict__ e_norm) {
    int k = blockIdx.x;
    int lane = threadIdx.x; // 64
    float4 v = reinterpret_cast<const float4*>(emb + (size_t)k * DD)[lane];
    float s = v.x * v.x + v.y * v.y + v.z * v.z + v.w * v.w;
    #pragma unroll
    for (int off = 32; off; off >>= 1) s += __shfl_down(s, off);
    if (lane == 0) e_norm[k] = s;
}

// ---------------- K2: 1x1 conv -> flat[N, D] ----------------
// block: 256 threads, 32 pixels per block; thread t computes output channel d=t
__global__ __launch_bounds__(256) void k_conv(const float* __restrict__ x,
                                              const float* __restrict__ w,
                                              const float* __restrict__ bias,
                                              float* __restrict__ flat) {
    __shared__ __align__(16) float xt[32][260]; // [pixel][channel], pad row to 260
    int t = threadIdx.x;
    int n0 = blockIdx.x * 32;
    int b = n0 >> 10, hw0 = n0 & 1023;
    const float* xb = x + (size_t)b * (CC * HW) + hw0;

    int p = t & 31, cg = t >> 5; // 32 pixels x 8 channel-groups
    #pragma unroll
    for (int it = 0; it < 32; ++it) {
        int c = it * 8 + cg;
        xt[p][c] = xb[c * HW + p];
    }
    __syncthreads();

    int d = t;
    float acc[32];
    float bv = bias[d];
    #pragma unroll
    for (int i = 0; i < 32; ++i) acc[i] = bv;

    const float4* wrow = reinterpret_cast<const float4*>(w + (size_t)d * CC);
    for (int c4 = 0; c4 < 64; ++c4) {
        float4 w4 = wrow[c4];
        #pragma unroll
        for (int pp = 0; pp < 32; ++pp) {
            float4 x4 = *reinterpret_cast<const float4*>(&xt[pp][c4 * 4]);
            acc[pp] = fmaf(w4.x, x4.x, acc[pp]);
            acc[pp] = fmaf(w4.y, x4.y, acc[pp]);
            acc[pp] = fmaf(w4.z, x4.z, acc[pp]);
            acc[pp] = fmaf(w4.w, x4.w, acc[pp]);
        }
    }
    #pragma unroll
    for (int pp = 0; pp < 32; ++pp)
        flat[(size_t)(n0 + pp) * DD + d] = acc[pp];
}

// ---------------- K3: GEMM + running argmin ----------------
// score[n][k] = e_norm[k] - 2 * dot(flat[n], emb[k]); idx[n] = argmin_k
// BM=128 pixels, BN=128 codes, Bd=32, 256 threads, 8x8 per thread.
__global__ __launch_bounds__(256) void k_argmin(const float* __restrict__ flat,
                                                const float* __restrict__ emb,
                                                const float* __restrict__ e_norm,
                                                int* __restrict__ idx) {
    __shared__ __align__(16) float At[128][36]; // pixels x d-chunk (pad 36)
    __shared__ __align__(16) float Bt[128][36]; // codes  x d-chunk
    __shared__ float rv[128][16];
    __shared__ int   ri[128][16];

    int t = threadIdx.x;
    int n0 = blockIdx.x * 128;
    int tp = t & 15, tk = t >> 4;

    float minv[8];
    int   mini[8];
    #pragma unroll
    for (int i = 0; i < 8; ++i) { minv[i] = 3.4e38f; mini[i] = 0; }

    int sr  = t >> 3;       // 0..31 staging row group
    int sc4 = (t & 7) * 4;  // 0,4,...,28

    for (int kc = 0; kc < KK; kc += 128) {
        float acc[8][8];
        #pragma unroll
        for (int i = 0; i < 8; ++i)
            #pragma unroll
            for (int j = 0; j < 8; ++j) acc[i][j] = 0.0f;

        for (int d0 = 0; d0 < DD; d0 += 32) {
            __syncthreads(); // previous tile fully consumed
            #pragma unroll
            for (int s = 0; s < 4; ++s) {
                int r = sr + 32 * s;
                *reinterpret_cast<float4*>(&At[r][sc4]) =
                    *reinterpret_cast<const float4*>(&flat[(size_t)(n0 + r) * DD + d0 + sc4]);
                *reinterpret_cast<float4*>(&Bt[r][sc4]) =
                    *reinterpret_cast<const float4*>(&emb[(size_t)(kc + r) * DD + d0 + sc4]);
            }
            __syncthreads();
            #pragma unroll
            for (int dd = 0; dd < 32; dd += 4) {
                float4 a4[8];
                #pragma unroll
                for (int i = 0; i < 8; ++i)
                    a4[i] = *reinterpret_cast<const float4*>(&At[tp + 16 * i][dd]);
                #pragma unroll
                for (int j = 0; j < 8; ++j) {
                    float4 b4 = *reinterpret_cast<const float4*>(&Bt[tk + 16 * j][dd]);
                    #pragma unroll
                    for (int i = 0; i < 8; ++i) {
                        acc[i][j] = fmaf(a4[i].x, b4.x, acc[i][j]);
                        acc[i][j] = fmaf(a4[i].y, b4.y, acc[i][j]);
                        acc[i][j] = fmaf(a4[i].z, b4.z, acc[i][j]);
                        acc[i][j] = fmaf(a4[i].w, b4.w, acc[i][j]);
                    }
                }
            }
        }
        // fold this k-chunk into the running argmin
        #pragma unroll
        for (int j = 0; j < 8; ++j) {
            int k = kc + tk + 16 * j;
            float en = e_norm[k];
            #pragma unroll
            for (int i = 0; i < 8; ++i) {
                float sc = fmaf(-2.0f, acc[i][j], en);
                if (sc < minv[i]) { minv[i] = sc; mini[i] = k; }
            }
        }
    }

    #pragma unroll
    for (int i = 0; i < 8; ++i) {
        rv[tp + 16 * i][tk] = minv[i];
        ri[tp + 16 * i][tk] = mini[i];
    }
    __syncthreads();
    if (t < 128) {
        float bv = rv[t][0]; int bi = ri[t][0];
        #pragma unroll
        for (int q = 1; q < 16; ++q) {
            float v = rv[t][q]; int ii = ri[t][q];
            if (v < bv || (v == bv && ii < bi)) { bv = v; bi = ii; }
        }
        idx[n0 + t] = bi;
    }
}

// ---------------- K4: gather emb[idx] -> out[B,D,H,W], loss partial ----------------
__global__ __launch_bounds__(256) void k_gather(const float* __restrict__ emb,
                                                const float* __restrict__ flat,
                                                const int* __restrict__ idx,
                                                float* __restrict__ out,
                                                float* __restrict__ accum) {
    __shared__ float qt[256][33]; // [d][pixel], pad 33
    int t = threadIdx.x;
    int n0 = blockIdx.x * 32;
    int b = n0 >> 10, hw0 = n0 & 1023;

    float ss = 0.0f;
    for (int p = 0; p < 32; ++p) {
        int row = idx[n0 + p];
        float q = emb[(size_t)row * DD + t];
        float z = flat[(size_t)(n0 + p) * DD + t];
        float df = q - z;
        ss = fmaf(df, df, ss);
        qt[t][p] = q;
    }
    __syncthreads();

    int dg = t >> 5, p = t & 31;
    float* ob = out + (size_t)b * (DD * HW) + hw0;
    #pragma unroll
    for (int s = 0; s < 32; ++s) {
        int d = dg + 8 * s;
        ob[d * HW + p] = qt[d][p];
    }

    // block reduce squared error
    #pragma unroll
    for (int off = 32; off; off >>= 1) ss += __shfl_down(ss, off);
    __shared__ float wsum[4];
    if ((t & 63) == 0) wsum[t >> 6] = ss;
    __syncthreads();
    if (t == 0) atomicAdd(accum, wsum[0] + wsum[1] + wsum[2] + wsum[3]);
}

// ---------------- K5: histogram ----------------
__global__ void k_hist(const int* __restrict__ idx, int* __restrict__ counts) {
    int i = blockIdx.x * 256 + threadIdx.x;
    atomicAdd(&counts[idx[i]], 1);
}

// ---------------- K6: finalize loss + perplexity ----------------
__global__ void k_final(const int* __restrict__ counts, const float* __restrict__ accum,
                        float* __restrict__ out_scalars) {
    int t = threadIdx.x; // 256
    float s = 0.0f;
    #pragma unroll
    for (int q = 0; q < 16; ++q) {
        float p = (float)counts[t * 16 + q] * (1.0f / 32768.0f);
        s += p * logf(p + 1e-10f);
    }
    #pragma unroll
    for (int off = 32; off; off >>= 1) s += __shfl_down(s, off);
    __shared__ float wsum[4];
    if ((t & 63) == 0) wsum[t >> 6] = s;
    __syncthreads();
    if (t == 0) {
        float ent = wsum[0] + wsum[1] + wsum[2] + wsum[3];
        out_scalars[0] = accum[0] * (1.25f / (float)NELE); // q_loss + 0.25*e_loss, equal values
        out_scalars[1] = expf(-ent);
    }
}

extern "C" void kernel_launch(void* const* d_in, const int* in_sizes, int n_in,
                              void* d_out, int out_size, void* d_ws, size_t ws_size,
                              hipStream_t stream) {
    const float* x    = (const float*)d_in[0];
    const float* w    = (const float*)d_in[1];
    const float* bias = (const float*)d_in[2];
    const float* emb  = (const float*)d_in[3];
    float* out = (float*)d_out;

    char* ws = (char*)d_ws;
    float* flat   = (float*)ws;                              // 33,554,432 B
    float* e_norm = (float*)(ws + 33554432);                 // 16,384 B
    int*   idx    = (int*)  (ws + 33554432 + 16384);         // 131,072 B
    int*   counts = (int*)  (ws + 33554432 + 16384 + 131072);// 16,384 B
    float* accum  = (float*)(ws + 33554432 + 16384 + 131072 + 16384); // 8 B

    k_zero  <<<17,   256, 0, stream>>>(counts, accum);
    k_enorm <<<KK,    64, 0, stream>>>(emb, e_norm);
    k_conv  <<<1024, 256, 0, stream>>>(x, w, bias, flat);
    k_argmin<<<256,  256, 0, stream>>>(flat, emb, e_norm, idx);
    k_gather<<<1024, 256, 0, stream>>>(emb, flat, idx, out, accum);
    k_hist  <<<128,  256, 0, stream>>>(idx, counts);
    k_final <<<1,    256, 0, stream>>>(counts, accum, out + NELE);
}

// Round 2
// 544.449 us; speedup vs baseline: 2.4321x; 2.4321x over previous
//
#include <hip/hip_runtime.h>
#include <math.h>

#define BB   32
#define CC   256
#define HH   32
#define WW   32
#define DD   256
#define KK   4096
#define HW   1024
#define NPIX 32768   // B*H*W
#define NELE 8388608 // B*D*H*W
#define EPS_REPAIR 1e-5f

typedef unsigned short ushort_t;
typedef __attribute__((ext_vector_type(8))) short short8;
typedef __attribute__((ext_vector_type(4))) float f32x4;

__device__ __forceinline__ unsigned short f2bf(float v) {
    union { float f; unsigned u; } c; c.f = v;
    unsigned r = c.u + 0x7FFFu + ((c.u >> 16) & 1u);  // RN-even
    return (unsigned short)(r >> 16);
}
__device__ __forceinline__ float bf2f(unsigned short b) {
    union { unsigned u; float f; } c; c.u = ((unsigned)b) << 16;
    return c.f;
}
__device__ __forceinline__ void gll16(const void* g, void* l) {
    __builtin_amdgcn_global_load_lds(
        (const __attribute__((address_space(1))) void*)g,
        (__attribute__((address_space(3))) void*)l, 16, 0, 0);
}

// ---------------- K0: zero counts + accumulators ----------------
__global__ void k_zero(int* __restrict__ counts, float* __restrict__ accum) {
    int i = blockIdx.x * 256 + threadIdx.x;
    if (i < KK) counts[i] = 0;
    if (i < 2)  accum[i]  = 0.0f;
}

// ---------------- K1: pack emb -> Bp=[bh|bh|bl] bf16, e_norm ----------------
__global__ void k_packB(const float* __restrict__ emb, ushort_t* __restrict__ Bp,
                        float* __restrict__ e_norm) {
    int k = blockIdx.x;
    int lane = threadIdx.x; // 64
    float4 v = reinterpret_cast<const float4*>(emb + (size_t)k * DD)[lane];
    float s = v.x * v.x + v.y * v.y + v.z * v.z + v.w * v.w;
    float vv[4] = {v.x, v.y, v.z, v.w};
    ushort_t* row = Bp + (size_t)k * 768 + lane * 4;
    #pragma unroll
    for (int c = 0; c < 4; ++c) {
        unsigned short h = f2bf(vv[c]);
        unsigned short l = f2bf(vv[c] - bf2f(h));
        row[c] = h; row[256 + c] = h; row[512 + c] = l;
    }
    #pragma unroll
    for (int off = 32; off; off >>= 1) s += __shfl_down(s, off);
    if (lane == 0) e_norm[k] = s;
}

// ---------------- K2: 1x1 conv -> A2=[zh|zl] bf16 pairs [N][512] ----------------
__global__ __launch_bounds__(256) void k_conv(const float* __restrict__ x,
                                              const float* __restrict__ w,
                                              const float* __restrict__ bias,
                                              ushort_t* __restrict__ A2) {
    __shared__ __align__(16) float xt[32][260];
    int t = threadIdx.x;
    int n0 = blockIdx.x * 32;
    int b = n0 >> 10, hw0 = n0 & 1023;
    const float* xb = x + (size_t)b * (CC * HW) + hw0;

    int p = t & 31, cg = t >> 5;
    #pragma unroll
    for (int it = 0; it < 32; ++it) {
        int c = it * 8 + cg;
        xt[p][c] = xb[c * HW + p];
    }
    __syncthreads();

    int d = t;
    float acc[32];
    float bv = bias[d];
    #pragma unroll
    for (int i = 0; i < 32; ++i) acc[i] = bv;

    const float4* wrow = reinterpret_cast<const float4*>(w + (size_t)d * CC);
    for (int c4 = 0; c4 < 64; ++c4) {
        float4 w4 = wrow[c4];
        #pragma unroll
        for (int pp = 0; pp < 32; ++pp) {
            float4 x4 = *reinterpret_cast<const float4*>(&xt[pp][c4 * 4]);
            acc[pp] = fmaf(w4.x, x4.x, acc[pp]);
            acc[pp] = fmaf(w4.y, x4.y, acc[pp]);
            acc[pp] = fmaf(w4.z, x4.z, acc[pp]);
            acc[pp] = fmaf(w4.w, x4.w, acc[pp]);
        }
    }
    #pragma unroll
    for (int pp = 0; pp < 32; ++pp) {
        float v = acc[pp];
        unsigned short h = f2bf(v);
        unsigned short l = f2bf(v - bf2f(h));
        ushort_t* arow = A2 + (size_t)(n0 + pp) * 512;
        arow[d] = h; arow[256 + d] = l;
    }
}

// ---------------- K3: MFMA GEMM + per-pixel top2 over codes ----------------
// score[n][k] = e_norm[k] - 2*dot(z_n, e_k), dot via bf16 split GEMM K'=768.
// grid = 256 m-blocks x 4 code-chunks (1024 codes each). 128x128 tiles,
// 4 waves of 64x64, BK=64, global_load_lds 16B staging.
__global__ __launch_bounds__(256, 2) void k_mfma_top2(
    const ushort_t* __restrict__ A2,   // [NPIX][512]  = [zh|zl]
    const ushort_t* __restrict__ Bp,   // [KK][768]    = [bh|bh|bl]
    const float* __restrict__ e_norm,
    float* __restrict__ tv1, int* __restrict__ ti1,
    float* __restrict__ tv2, int* __restrict__ ti2) {
    __shared__ __align__(16) short As[128][64];
    __shared__ __align__(16) short Bs[128][64];
    __shared__ float mgv[128][2][2];
    __shared__ int   mgi[128][2][2];

    const int t  = threadIdx.x;
    const int mb = blockIdx.x >> 2, ch = blockIdx.x & 3;
    const int n0 = mb * 128, c0 = ch * 1024;
    const int w  = t >> 6, lane = t & 63;
    const int wr = w >> 1, wc = w & 1;
    const int lr = lane & 15, lg = lane >> 4;

    const int srow = t >> 3;        // staging row (+32*s)
    const int scol = (t & 7) * 8;   // staging col in shorts

    float v1[4][4], v2r[4][4];
    int   i1[4][4], i2r[4][4];
    #pragma unroll
    for (int m = 0; m < 4; ++m)
        #pragma unroll
        for (int j = 0; j < 4; ++j) {
            v1[m][j] = 3.0e38f; v2r[m][j] = 3.0e38f;
            i1[m][j] = 0x7FFFFFFF; i2r[m][j] = 0x7FFFFFFF;
        }

    for (int sub = 0; sub < 8; ++sub) {
        const int code0 = c0 + sub * 128;
        f32x4 acc[4][4];
        const f32x4 vz = {0.f, 0.f, 0.f, 0.f};
        #pragma unroll
        for (int m = 0; m < 4; ++m)
            #pragma unroll
            for (int n = 0; n < 4; ++n) acc[m][n] = vz;

        for (int ks = 0; ks < 12; ++ks) {
            // A' = [zh | zl | zh]: third segment re-reads cols 0..255
            const int Acol = (ks < 8) ? ks * 64 : (ks - 8) * 64;
            const int Bcol = ks * 64;
            __syncthreads();   // previous tile fully consumed
            #pragma unroll
            for (int s = 0; s < 4; ++s) {
                const int r = srow + 32 * s;
                gll16(&A2[(size_t)(n0 + r) * 512 + Acol + scol], &As[r][scol]);
                gll16(&Bp[(size_t)(code0 + r) * 768 + Bcol + scol], &Bs[r][scol]);
            }
            __syncthreads();   // compiler drains vmcnt before barrier
            #pragma unroll
            for (int kk = 0; kk < 2; ++kk) {
                short8 a[4], b[4];
                #pragma unroll
                for (int m = 0; m < 4; ++m)
                    a[m] = *reinterpret_cast<const short8*>(
                        &As[wr * 64 + m * 16 + lr][kk * 32 + lg * 8]);
                #pragma unroll
                for (int n = 0; n < 4; ++n)
                    b[n] = *reinterpret_cast<const short8*>(
                        &Bs[wc * 64 + n * 16 + lr][kk * 32 + lg * 8]);
                #pragma unroll
                for (int m = 0; m < 4; ++m)
                    #pragma unroll
                    for (int n = 0; n < 4; ++n)
                        acc[m][n] = __builtin_amdgcn_mfma_f32_16x16x32_bf16(
                            a[m], b[n], acc[m][n], 0, 0, 0);
            }
        }
        // fold this 128-code sub-tile into running top2
        #pragma unroll
        for (int n = 0; n < 4; ++n) {
            const int col = code0 + wc * 64 + n * 16 + lr;
            const float en = e_norm[col];
            #pragma unroll
            for (int m = 0; m < 4; ++m)
                #pragma unroll
                for (int j = 0; j < 4; ++j) {
                    const float s = fmaf(-2.0f, acc[m][n][j], en);
                    const bool b1 = s < v1[m][j];
                    const bool b2 = s < v2r[m][j];
                    v2r[m][j] = b1 ? v1[m][j] : (b2 ? s : v2r[m][j]);
                    i2r[m][j] = b1 ? i1[m][j] : (b2 ? col : i2r[m][j]);
                    v1[m][j]  = b1 ? s   : v1[m][j];
                    i1[m][j]  = b1 ? col : i1[m][j];
                }
        }
    }

    // cross-lane top2 merge across the 16 lanes sharing each row
    #pragma unroll
    for (int mask = 1; mask <= 8; mask <<= 1) {
        #pragma unroll
        for (int m = 0; m < 4; ++m)
            #pragma unroll
            for (int j = 0; j < 4; ++j) {
                const float ov1 = __shfl_xor(v1[m][j], mask);
                const int   oi1 = __shfl_xor(i1[m][j], mask);
                const float ov2 = __shfl_xor(v2r[m][j], mask);
                const int   oi2 = __shfl_xor(i2r[m][j], mask);
                const bool tb = (ov1 < v1[m][j]) || (ov1 == v1[m][j] && oi1 < i1[m][j]);
                const float w1 = tb ? ov1 : v1[m][j];  const int w1i = tb ? oi1 : i1[m][j];
                const float l1 = tb ? v1[m][j] : ov1;  const int l1i = tb ? i1[m][j] : oi1;
                const float c2 = tb ? ov2 : v2r[m][j]; const int c2i = tb ? oi2 : i2r[m][j];
                const bool t2b = (c2 < l1) || (c2 == l1 && c2i < l1i);
                v1[m][j] = w1; i1[m][j] = w1i;
                v2r[m][j] = t2b ? c2 : l1; i2r[m][j] = t2b ? c2i : l1i;
            }
    }
    // per-wave writers (one lane per 16-lane group) -> LDS
    if (lr == 0) {
        #pragma unroll
        for (int m = 0; m < 4; ++m)
            #pragma unroll
            for (int j = 0; j < 4; ++j) {
                const int r = wr * 64 + m * 16 + lg * 4 + j;
                mgv[r][wc][0] = v1[m][j];  mgv[r][wc][1] = v2r[m][j];
                mgi[r][wc][0] = i1[m][j];  mgi[r][wc][1] = i2r[m][j];
            }
    }
    __syncthreads();
    // merge the two column-halves (wc=0,1) per row, write chunk top2
    if (t < 128) {
        const float a1 = mgv[t][0][0], a2 = mgv[t][0][1];
        const int  ai1 = mgi[t][0][0], ai2 = mgi[t][0][1];
        const float b1 = mgv[t][1][0], b2 = mgv[t][1][1];
        const int  bi1 = mgi[t][1][0], bi2 = mgi[t][1][1];
        const bool tb = (b1 < a1) || (b1 == a1 && bi1 < ai1);
        const float w1 = tb ? b1 : a1;  const int w1i = tb ? bi1 : ai1;
        const float l1 = tb ? a1 : b1;  const int l1i = tb ? ai1 : bi1;
        const float c2 = tb ? b2 : a2;  const int c2i = tb ? bi2 : ai2;
        const bool t2b = (c2 < l1) || (c2 == l1 && c2i < l1i);
        const size_t o = (size_t)ch * NPIX + n0 + t;
        tv1[o] = w1; ti1[o] = w1i;
        tv2[o] = t2b ? c2 : l1; ti2[o] = t2b ? c2i : l1i;
    }
}

// ---------------- K4: merge 4 chunk-top2s, repair near-ties exactly ----------------
__global__ __launch_bounds__(256) void k_select(
    const float* __restrict__ tv1, const int* __restrict__ ti1,
    const float* __restrict__ tv2, const int* __restrict__ ti2,
    const ushort_t* __restrict__ A2, const float* __restrict__ emb,
    const float* __restrict__ e_norm, int* __restrict__ idx) {
    const int n = blockIdx.x * 256 + threadIdx.x;
    float g1 = tv1[n], g2 = tv2[n];
    int  gi1 = ti1[n], gi2 = ti2[n];
    #pragma unroll
    for (int c = 1; c < 4; ++c) {
        const size_t o = (size_t)c * NPIX + n;
        const float b1 = tv1[o], b2 = tv2[o];
        const int  bi1 = ti1[o], bi2 = ti2[o];
        const bool tb = (b1 < g1) || (b1 == g1 && bi1 < gi1);
        const float w1 = tb ? b1 : g1;  const int w1i = tb ? bi1 : gi1;
        const float l1 = tb ? g1 : b1;  const int l1i = tb ? gi1 : bi1;
        const float c2 = tb ? b2 : g2;  const int c2i = tb ? bi2 : gi2;
        const bool t2b = (c2 < l1) || (c2 == l1 && c2i < l1i);
        g1 = w1; gi1 = w1i;
        g2 = t2b ? c2 : l1; gi2 = t2b ? c2i : l1i;
    }
    int best = gi1;
    if (g2 - g1 < EPS_REPAIR) {  // exact fp32 re-rank of the two candidates
        const ushort_t* za = A2 + (size_t)n * 512;
        const float* e1 = emb + (size_t)gi1 * DD;
        const float* e2 = emb + (size_t)gi2 * DD;
        float d1 = 0.f, d2 = 0.f;
        for (int d = 0; d < DD; ++d) {
            const float z = bf2f(za[d]) + bf2f(za[256 + d]);
            d1 = fmaf(z, e1[d], d1);
            d2 = fmaf(z, e2[d], d2);
        }
        const float s1 = e_norm[gi1] - 2.f * d1;
        const float s2 = e_norm[gi2] - 2.f * d2;
        best = (s2 < s1 || (s2 == s1 && gi2 < gi1)) ? gi2 : gi1;
    }
    idx[n] = best;
}

// ---------------- K5: gather emb[idx] -> out[B,D,H,W], loss partial ----------------
__global__ __launch_bounds__(256) void k_gather(const float* __restrict__ emb,
                                                const ushort_t* __restrict__ A2,
                                                const int* __restrict__ idx,
                                                float* __restrict__ out,
                                                float* __restrict__ accum) {
    __shared__ float qt[256][33];
    int t = threadIdx.x;
    int n0 = blockIdx.x * 32;
    int b = n0 >> 10, hw0 = n0 & 1023;

    float ss = 0.0f;
    for (int p = 0; p < 32; ++p) {
        int row = idx[n0 + p];
        float q = emb[(size_t)row * DD + t];
        const ushort_t* za = A2 + (size_t)(n0 + p) * 512;
        float z = bf2f(za[t]) + bf2f(za[256 + t]);
        float df = q - z;
        ss = fmaf(df, df, ss);
        qt[t][p] = q;
    }
    __syncthreads();

    int dg = t >> 5, p = t & 31;
    float* ob = out + (size_t)b * (DD * HW) + hw0;
    #pragma unroll
    for (int s = 0; s < 32; ++s) {
        int d = dg + 8 * s;
        ob[d * HW + p] = qt[d][p];
    }

    #pragma unroll
    for (int off = 32; off; off >>= 1) ss += __shfl_down(ss, off);
    __shared__ float wsum[4];
    if ((t & 63) == 0) wsum[t >> 6] = ss;
    __syncthreads();
    if (t == 0) atomicAdd(accum, wsum[0] + wsum[1] + wsum[2] + wsum[3]);
}

// ---------------- K6: histogram ----------------
__global__ void k_hist(const int* __restrict__ idx, int* __restrict__ counts) {
    int i = blockIdx.x * 256 + threadIdx.x;
    atomicAdd(&counts[idx[i]], 1);
}

// ---------------- K7: finalize loss + perplexity ----------------
__global__ void k_final(const int* __restrict__ counts, const float* __restrict__ accum,
                        float* __restrict__ out_scalars) {
    int t = threadIdx.x; // 256
    float s = 0.0f;
    #pragma unroll
    for (int q = 0; q < 16; ++q) {
        float p = (float)counts[t * 16 + q] * (1.0f / 32768.0f);
        s += p * logf(p + 1e-10f);
    }
    #pragma unroll
    for (int off = 32; off; off >>= 1) s += __shfl_down(s, off);
    __shared__ float wsum[4];
    if ((t & 63) == 0) wsum[t >> 6] = s;
    __syncthreads();
    if (t == 0) {
        float ent = wsum[0] + wsum[1] + wsum[2] + wsum[3];
        out_scalars[0] = accum[0] * (1.25f / (float)NELE);
        out_scalars[1] = expf(-ent);
    }
}

extern "C" void kernel_launch(void* const* d_in, const int* in_sizes, int n_in,
                              void* d_out, int out_size, void* d_ws, size_t ws_size,
                              hipStream_t stream) {
    const float* x    = (const float*)d_in[0];
    const float* w    = (const float*)d_in[1];
    const float* bias = (const float*)d_in[2];
    const float* emb  = (const float*)d_in[3];
    float* out = (float*)d_out;

    char* ws = (char*)d_ws;
    ushort_t* A2   = (ushort_t*)ws;                      // 33,554,432 B
    ushort_t* Bp   = (ushort_t*)(ws + 33554432);         //  6,291,456 B
    float* e_norm  = (float*)(ws + 39845888);            //     16,384 B
    int*   idx     = (int*)  (ws + 39862272);            //    131,072 B
    int*   counts  = (int*)  (ws + 39993344);            //     16,384 B
    float* accum   = (float*)(ws + 40009728);            //        256 B
    float* tv1     = (float*)(ws + 40009984);            //    524,288 B
    int*   ti1     = (int*)  (ws + 40534272);            //    524,288 B
    float* tv2     = (float*)(ws + 41058560);            //    524,288 B
    int*   ti2     = (int*)  (ws + 41582848);            //    524,288 B
    // total ~42.1 MB

    k_zero     <<<17,   256, 0, stream>>>(counts, accum);
    k_packB    <<<KK,    64, 0, stream>>>(emb, Bp, e_norm);
    k_conv     <<<1024, 256, 0, stream>>>(x, w, bias, A2);
    k_mfma_top2<<<1024, 256, 0, stream>>>(A2, Bp, e_norm, tv1, ti1, tv2, ti2);
    k_select   <<<128,  256, 0, stream>>>(tv1, ti1, tv2, ti2, A2, emb, e_norm, idx);
    k_gather   <<<1024, 256, 0, stream>>>(emb, A2, idx, out, accum);
    k_hist     <<<128,  256, 0, stream>>>(idx, counts);
    k_final    <<<1,    256, 0, stream>>>(counts, accum, out + NELE);
}

// Round 3
// 463.848 us; speedup vs baseline: 2.8547x; 1.1738x over previous
//
#include <hip/hip_runtime.h>
#include <math.h>

#define BB   32
#define CC   256
#define DD   256
#define KK   4096
#define HW   1024
#define NPIX 32768   // B*H*W
#define NELE 8388608 // B*D*H*W
#define EPS_REPAIR 1e-6f

typedef unsigned short ushort_t;
typedef __attribute__((ext_vector_type(8))) short short8;
typedef __attribute__((ext_vector_type(4))) float f32x4;

__device__ __forceinline__ unsigned short f2bf(float v) {
    union { float f; unsigned u; } c; c.f = v;
    unsigned r = c.u + 0x7FFFu + ((c.u >> 16) & 1u);  // RN-even
    return (unsigned short)(r >> 16);
}
__device__ __forceinline__ float bf2f(unsigned short b) {
    union { unsigned u; float f; } c; c.u = ((unsigned)b) << 16;
    return c.f;
}
__device__ __forceinline__ void gll16(const void* g, void* l) {
    __builtin_amdgcn_global_load_lds(
        (const __attribute__((address_space(1))) void*)g,
        (__attribute__((address_space(3))) void*)l, 16, 0, 0);
}

// ---------------- K1: pack emb -> Bp=[bh|bh|bl] bf16, e_norm; fused zeroing ----------------
__global__ void k_packB(const float* __restrict__ emb, ushort_t* __restrict__ Bp,
                        float* __restrict__ e_norm, int* __restrict__ counts,
                        float* __restrict__ accum) {
    int k = blockIdx.x;
    int lane = threadIdx.x; // 64
    if (lane == 0) counts[k] = 0;
    if (k == 0 && lane < 2) accum[lane] = 0.0f;
    float4 v = reinterpret_cast<const float4*>(emb + (size_t)k * DD)[lane];
    float s = v.x * v.x + v.y * v.y + v.z * v.z + v.w * v.w;
    float vv[4] = {v.x, v.y, v.z, v.w};
    ushort_t* row = Bp + (size_t)k * 768 + lane * 4;
    #pragma unroll
    for (int c = 0; c < 4; ++c) {
        unsigned short h = f2bf(vv[c]);
        unsigned short l = f2bf(vv[c] - bf2f(h));
        row[c] = h; row[256 + c] = h; row[512 + c] = l;
    }
    #pragma unroll
    for (int off = 32; off; off >>= 1) s += __shfl_down(s, off);
    if (lane == 0) e_norm[k] = s;
}

// ---------------- K2: 1x1 conv -> A2=[zh|zl] bf16 pairs [N][512] ----------------
__global__ __launch_bounds__(256) void k_conv(const float* __restrict__ x,
                                              const float* __restrict__ w,
                                              const float* __restrict__ bias,
                                              ushort_t* __restrict__ A2) {
    __shared__ __align__(16) float xt[32][260];
    int t = threadIdx.x;
    int n0 = blockIdx.x * 32;
    int b = n0 >> 10, hw0 = n0 & 1023;
    const float* xb = x + (size_t)b * (CC * HW) + hw0;

    int p = t & 31, cg = t >> 5;
    #pragma unroll
    for (int it = 0; it < 32; ++it) {
        int c = it * 8 + cg;
        xt[p][c] = xb[c * HW + p];
    }
    __syncthreads();

    int d = t;
    float acc[32];
    float bv = bias[d];
    #pragma unroll
    for (int i = 0; i < 32; ++i) acc[i] = bv;

    const float4* wrow = reinterpret_cast<const float4*>(w + (size_t)d * CC);
    for (int c4 = 0; c4 < 64; ++c4) {
        float4 w4 = wrow[c4];
        #pragma unroll
        for (int pp = 0; pp < 32; ++pp) {
            float4 x4 = *reinterpret_cast<const float4*>(&xt[pp][c4 * 4]);
            acc[pp] = fmaf(w4.x, x4.x, acc[pp]);
            acc[pp] = fmaf(w4.y, x4.y, acc[pp]);
            acc[pp] = fmaf(w4.z, x4.z, acc[pp]);
            acc[pp] = fmaf(w4.w, x4.w, acc[pp]);
        }
    }
    #pragma unroll
    for (int pp = 0; pp < 32; ++pp) {
        float v = acc[pp];
        unsigned short h = f2bf(v);
        unsigned short l = f2bf(v - bf2f(h));
        ushort_t* arow = A2 + (size_t)(n0 + pp) * 512;
        arow[d] = h; arow[256 + d] = l;
    }
}

// ---------------- K3: MFMA GEMM + per-pixel top2 over codes ----------------
// 128x128 tiles, 4 waves of 64x64, BK=64, double-buffered LDS (2-phase),
// XOR-swizzled LDS (linear dest + pre-swizzled global src + swizzled read),
// XCD-aware block mapping: each XCD works one 1024-code chunk (L2-resident B).
__global__ __launch_bounds__(256, 2) void k_mfma_top2(
    const ushort_t* __restrict__ A2,   // [NPIX][512]  = [zh|zl]
    const ushort_t* __restrict__ Bp,   // [KK][768]    = [bh|bh|bl]
    const float* __restrict__ e_norm,
    float* __restrict__ tv1, int* __restrict__ ti1,
    float* __restrict__ tv2, int* __restrict__ ti2) {
    __shared__ __align__(16) short smem[2][2][128][64];  // [buf][A/B][row][col] = 64 KB

    const int t = threadIdx.x;
    // XCD mapping: xcd = bid&7 (dispatch round-robin); each XCD -> one code chunk
    const int xcd = blockIdx.x & 7, slot = blockIdx.x >> 3;
    const int ch = xcd >> 1;
    const int mb = ((xcd & 1) << 7) | slot;       // 0..255
    const int n0 = mb * 128, c0 = ch * 1024;
    const int w = t >> 6, lane = t & 63;
    const int wr = w >> 1, wc = w & 1;
    const int lr = lane & 15, lg = lane >> 4;

    const int srow = t >> 3;                       // staging row (+32*s)
    const int g    = t & 7;                        // dest granule (16B units)
    const int sg   = (g ^ (srow & 7)) * 8;         // swizzled SOURCE col (shorts)

    // swizzled read cols (shorts): global granule q=kk*4+lg lives at q^(row&7)
    const int rc0 = ((lg)     ^ (lr & 7)) * 8;     // kk=0
    const int rc1 = ((4 + lg) ^ (lr & 7)) * 8;     // kk=1

    float v1[4][4], v2r[4][4];
    int   i1[4][4], i2r[4][4];
    #pragma unroll
    for (int m = 0; m < 4; ++m)
        #pragma unroll
        for (int j = 0; j < 4; ++j) {
            v1[m][j] = 3.0e38f; v2r[m][j] = 3.0e38f;
            i1[m][j] = 0x7FFFFFFF; i2r[m][j] = 0x7FFFFFFF;
        }

    auto stage = [&](int buf, int sb, int kstep) {
        const int code0 = c0 + sb * 128;
        const int Acol = ((kstep < 8) ? kstep : kstep - 8) * 64;  // A'=[zh|zl|zh]
        const int Bcol = kstep * 64;
        #pragma unroll
        for (int s = 0; s < 4; ++s) {
            const int r = srow + 32 * s;
            gll16(&A2[(size_t)(n0 + r) * 512 + Acol + sg], &smem[buf][0][r][g * 8]);
            gll16(&Bp[(size_t)(code0 + r) * 768 + Bcol + sg], &smem[buf][1][r][g * 8]);
        }
    };

    f32x4 acc[4][4];
    stage(0, 0, 0);
    __syncthreads();                 // vmcnt(0) drain + barrier
    int cur = 0, sub = 0, ks = 0;
    while (true) {
        int nks = ks + 1, nsub = sub;
        if (nks == 12) { nks = 0; nsub = sub + 1; }
        if (nsub < 8) stage(cur ^ 1, nsub, nks);   // next tile in flight during compute

        if (ks == 0) {
            const f32x4 vz = {0.f, 0.f, 0.f, 0.f};
            #pragma unroll
            for (int m = 0; m < 4; ++m)
                #pragma unroll
                for (int n = 0; n < 4; ++n) acc[m][n] = vz;
        }
        #pragma unroll
        for (int kk = 0; kk < 2; ++kk) {
            const int rc = kk ? rc1 : rc0;
            short8 a[4], b[4];
            #pragma unroll
            for (int m = 0; m < 4; ++m)
                a[m] = *reinterpret_cast<const short8*>(
                    &smem[cur][0][wr * 64 + m * 16 + lr][rc]);
            #pragma unroll
            for (int n = 0; n < 4; ++n)
                b[n] = *reinterpret_cast<const short8*>(
                    &smem[cur][1][wc * 64 + n * 16 + lr][rc]);
            #pragma unroll
            for (int m = 0; m < 4; ++m)
                #pragma unroll
                for (int n = 0; n < 4; ++n)
                    acc[m][n] = __builtin_amdgcn_mfma_f32_16x16x32_bf16(
                        a[m], b[n], acc[m][n], 0, 0, 0);
        }
        if (ks == 11) {  // fold this 128-code sub-tile into running top2 (acc dies here)
            const int code0 = c0 + sub * 128;
            #pragma unroll
            for (int n = 0; n < 4; ++n) {
                const int col = code0 + wc * 64 + n * 16 + lr;
                const float en = e_norm[col];
                #pragma unroll
                for (int m = 0; m < 4; ++m)
                    #pragma unroll
                    for (int j = 0; j < 4; ++j) {
                        const float s = fmaf(-2.0f, acc[m][n][j], en);
                        const bool b1 = s < v1[m][j];
                        const bool b2 = s < v2r[m][j];
                        v2r[m][j] = b1 ? v1[m][j] : (b2 ? s : v2r[m][j]);
                        i2r[m][j] = b1 ? i1[m][j] : (b2 ? col : i2r[m][j]);
                        v1[m][j]  = b1 ? s   : v1[m][j];
                        i1[m][j]  = b1 ? col : i1[m][j];
                    }
            }
        }
        __syncthreads();             // drains next-tile loads; all reads of cur done
        cur ^= 1; ks = nks; sub = nsub;
        if (sub == 8) break;
    }

    // cross-lane top2 merge across the 16 lanes sharing each row
    #pragma unroll
    for (int mask = 1; mask <= 8; mask <<= 1) {
        #pragma unroll
        for (int m = 0; m < 4; ++m)
            #pragma unroll
            for (int j = 0; j < 4; ++j) {
                const float ov1 = __shfl_xor(v1[m][j], mask);
                const int   oi1 = __shfl_xor(i1[m][j], mask);
                const float ov2 = __shfl_xor(v2r[m][j], mask);
                const int   oi2 = __shfl_xor(i2r[m][j], mask);
                const bool tb = (ov1 < v1[m][j]) || (ov1 == v1[m][j] && oi1 < i1[m][j]);
                const float w1 = tb ? ov1 : v1[m][j];  const int w1i = tb ? oi1 : i1[m][j];
                const float l1 = tb ? v1[m][j] : ov1;  const int l1i = tb ? i1[m][j] : oi1;
                const float c2 = tb ? ov2 : v2r[m][j]; const int c2i = tb ? oi2 : i2r[m][j];
                const bool t2b = (c2 < l1) || (c2 == l1 && c2i < l1i);
                v1[m][j] = w1; i1[m][j] = w1i;
                v2r[m][j] = t2b ? c2 : l1; i2r[m][j] = t2b ? c2i : l1i;
            }
    }
    // alias merge scratch onto smem (all LDS reads done at loop-end barrier)
    float* mgv = (float*)&smem[0][0][0][0];                    // [128][2][2] floats (2 KB)
    int*   mgi = (int*)((char*)&smem[0][0][0][0] + 2048);      // [128][2][2] ints  (2 KB)
    if (lr == 0) {
        #pragma unroll
        for (int m = 0; m < 4; ++m)
            #pragma unroll
            for (int j = 0; j < 4; ++j) {
                const int r = wr * 64 + m * 16 + lg * 4 + j;
                mgv[(r * 2 + wc) * 2 + 0] = v1[m][j];  mgv[(r * 2 + wc) * 2 + 1] = v2r[m][j];
                mgi[(r * 2 + wc) * 2 + 0] = i1[m][j];  mgi[(r * 2 + wc) * 2 + 1] = i2r[m][j];
            }
    }
    __syncthreads();
    if (t < 128) {
        const float a1 = mgv[(t * 2 + 0) * 2 + 0], a2 = mgv[(t * 2 + 0) * 2 + 1];
        const int  ai1 = mgi[(t * 2 + 0) * 2 + 0], ai2 = mgi[(t * 2 + 0) * 2 + 1];
        const float b1 = mgv[(t * 2 + 1) * 2 + 0], b2 = mgv[(t * 2 + 1) * 2 + 1];
        const int  bi1 = mgi[(t * 2 + 1) * 2 + 0], bi2 = mgi[(t * 2 + 1) * 2 + 1];
        const bool tb = (b1 < a1) || (b1 == a1 && bi1 < ai1);
        const float w1 = tb ? b1 : a1;  const int w1i = tb ? bi1 : ai1;
        const float l1 = tb ? a1 : b1;  const int l1i = tb ? ai1 : bi1;
        const float c2 = tb ? b2 : a2;  const int c2i = tb ? bi2 : ai2;
        const bool t2b = (c2 < l1) || (c2 == l1 && c2i < l1i);
        const size_t o = (size_t)ch * NPIX + n0 + t;
        tv1[o] = w1; ti1[o] = w1i;
        tv2[o] = t2b ? c2 : l1; ti2[o] = t2b ? c2i : l1i;
    }
}

// ---------------- K4: merge 4 chunk-top2s, repair near-ties exactly; fused histogram ----------------
__global__ __launch_bounds__(256) void k_select(
    const float* __restrict__ tv1, const int* __restrict__ ti1,
    const float* __restrict__ tv2, const int* __restrict__ ti2,
    const ushort_t* __restrict__ A2, const float* __restrict__ emb,
    const float* __restrict__ e_norm, int* __restrict__ idx,
    int* __restrict__ counts) {
    const int n = blockIdx.x * 256 + threadIdx.x;
    float g1 = tv1[n], g2 = tv2[n];
    int  gi1 = ti1[n], gi2 = ti2[n];
    #pragma unroll
    for (int c = 1; c < 4; ++c) {
        const size_t o = (size_t)c * NPIX + n;
        const float b1 = tv1[o], b2 = tv2[o];
        const int  bi1 = ti1[o], bi2 = ti2[o];
        const bool tb = (b1 < g1) || (b1 == g1 && bi1 < gi1);
        const float w1 = tb ? b1 : g1;  const int w1i = tb ? bi1 : gi1;
        const float l1 = tb ? g1 : b1;  const int l1i = tb ? gi1 : bi1;
        const float c2 = tb ? b2 : g2;  const int c2i = tb ? bi2 : gi2;
        const bool t2b = (c2 < l1) || (c2 == l1 && c2i < l1i);
        g1 = w1; gi1 = w1i;
        g2 = t2b ? c2 : l1; gi2 = t2b ? c2i : l1i;
    }
    int best = gi1;
    if (g2 - g1 < EPS_REPAIR) {  // exact fp32 re-rank of the two candidates
        const ushort_t* za = A2 + (size_t)n * 512;
        const float4* e1 = reinterpret_cast<const float4*>(emb + (size_t)gi1 * DD);
        const float4* e2 = reinterpret_cast<const float4*>(emb + (size_t)gi2 * DD);
        float d1 = 0.f, d2 = 0.f;
        for (int q = 0; q < 64; ++q) {
            const float4 a1 = e1[q], a2 = e2[q];
            #pragma unroll
            for (int c = 0; c < 4; ++c) {
                const int d = q * 4 + c;
                const float z = bf2f(za[d]) + bf2f(za[256 + d]);
                const float ev1 = (&a1.x)[c], ev2 = (&a2.x)[c];
                d1 = fmaf(z, ev1, d1);
                d2 = fmaf(z, ev2, d2);
            }
        }
        const float s1 = e_norm[gi1] - 2.f * d1;
        const float s2 = e_norm[gi2] - 2.f * d2;
        best = (s2 < s1 || (s2 == s1 && gi2 < gi1)) ? gi2 : gi1;
    }
    idx[n] = best;
    atomicAdd(&counts[best], 1);
}

// ---------------- K5: gather emb[idx] -> out[B,D,H,W], loss partial ----------------
__global__ __launch_bounds__(256) void k_gather(const float* __restrict__ emb,
                                                const ushort_t* __restrict__ A2,
                                                const int* __restrict__ idx,
                                                float* __restrict__ out,
                                                float* __restrict__ accum) {
    __shared__ float qt[256][33];
    int t = threadIdx.x;
    int n0 = blockIdx.x * 32;
    int b = n0 >> 10, hw0 = n0 & 1023;

    float ss = 0.0f;
    for (int p = 0; p < 32; ++p) {
        int row = idx[n0 + p];
        float q = emb[(size_t)row * DD + t];
        const ushort_t* za = A2 + (size_t)(n0 + p) * 512;
        float z = bf2f(za[t]) + bf2f(za[256 + t]);
        float df = q - z;
        ss = fmaf(df, df, ss);
        qt[t][p] = q;
    }
    __syncthreads();

    int dg = t >> 5, p = t & 31;
    float* ob = out + (size_t)b * (DD * HW) + hw0;
    #pragma unroll
    for (int s = 0; s < 32; ++s) {
        int d = dg + 8 * s;
        ob[d * HW + p] = qt[d][p];
    }

    #pragma unroll
    for (int off = 32; off; off >>= 1) ss += __shfl_down(ss, off);
    __shared__ float wsum[4];
    if ((t & 63) == 0) wsum[t >> 6] = ss;
    __syncthreads();
    if (t == 0) atomicAdd(accum, wsum[0] + wsum[1] + wsum[2] + wsum[3]);
}

// ---------------- K6: finalize loss + perplexity ----------------
__global__ void k_final(const int* __restrict__ counts, const float* __restrict__ accum,
                        float* __restrict__ out_scalars) {
    int t = threadIdx.x; // 256
    float s = 0.0f;
    #pragma unroll
    for (int q = 0; q < 16; ++q) {
        float p = (float)counts[t * 16 + q] * (1.0f / 32768.0f);
        s += p * logf(p + 1e-10f);
    }
    #pragma unroll
    for (int off = 32; off; off >>= 1) s += __shfl_down(s, off);
    __shared__ float wsum[4];
    if ((t & 63) == 0) wsum[t >> 6] = s;
    __syncthreads();
    if (t == 0) {
        float ent = wsum[0] + wsum[1] + wsum[2] + wsum[3];
        out_scalars[0] = accum[0] * (1.25f / (float)NELE);
        out_scalars[1] = expf(-ent);
    }
}

extern "C" void kernel_launch(void* const* d_in, const int* in_sizes, int n_in,
                              void* d_out, int out_size, void* d_ws, size_t ws_size,
                              hipStream_t stream) {
    const float* x    = (const float*)d_in[0];
    const float* w    = (const float*)d_in[1];
    const float* bias = (const float*)d_in[2];
    const float* emb  = (const float*)d_in[3];
    float* out = (float*)d_out;

    char* ws = (char*)d_ws;
    ushort_t* A2   = (ushort_t*)ws;                      // 33,554,432 B
    ushort_t* Bp   = (ushort_t*)(ws + 33554432);         //  6,291,456 B
    float* e_norm  = (float*)(ws + 39845888);            //     16,384 B
    int*   idx     = (int*)  (ws + 39862272);            //    131,072 B
    int*   counts  = (int*)  (ws + 39993344);            //     16,384 B
    float* accum   = (float*)(ws + 40009728);            //        256 B
    float* tv1     = (float*)(ws + 40009984);            //    524,288 B
    int*   ti1     = (int*)  (ws + 40534272);            //    524,288 B
    float* tv2     = (float*)(ws + 41058560);            //    524,288 B
    int*   ti2     = (int*)  (ws + 41582848);            //    524,288 B

    k_packB    <<<KK,    64, 0, stream>>>(emb, Bp, e_norm, counts, accum);
    k_conv     <<<1024, 256, 0, stream>>>(x, w, bias, A2);
    k_mfma_top2<<<1024, 256, 0, stream>>>(A2, Bp, e_norm, tv1, ti1, tv2, ti2);
    k_select   <<<128,  256, 0, stream>>>(tv1, ti1, tv2, ti2, A2, emb, e_norm, idx, counts);
    k_gather   <<<1024, 256, 0, stream>>>(emb, A2, idx, out, accum);
    k_final    <<<1,    256, 0, stream>>>(counts, accum, out + NELE);
}